// Round 13
// baseline (206.316 us; speedup 1.0000x reference)
//
#include <hip/hip_runtime.h>
#include <hip/hip_bf16.h>

// B=2, S=2048, D=1024, H=16, DH=64. f32 in/out; bf16 intermediates for MFMA.
#define Bn 2
#define Sn 2048
#define Dn 1024
#define Hn 16
#define DHn 64
#define Kd 1024
#define Mn (Bn * Sn)
#define LN10K 9.210340371976184f

typedef __attribute__((ext_vector_type(8))) short bf16x8;   // MFMA A/B frag
typedef __attribute__((ext_vector_type(4))) float f32x4;    // 16x16 C/D frag
typedef __attribute__((ext_vector_type(16))) float f32x16;  // 32x32 C/D frag

static __device__ __forceinline__ ushort f2bf(float f) {
    uint u = __float_as_uint(f);
    u += 0x7fff + ((u >> 16) & 1);   // round-nearest-even
    return (ushort)(u >> 16);
}
// packed f32x2 -> bf16x2 (RNE), lo = a, hi = b
static __device__ __forceinline__ uint cvtpk(float a, float b) {
    uint r;
    asm("v_cvt_pk_bf16_f32 %0, %1, %2" : "=v"(r) : "v"(a), "v"(b));
    return r;
}
// swap a.hi32lanes <-> b.lo32lanes
static __device__ __forceinline__ void plswap(uint& a, uint& b) {
    asm volatile("v_permlane32_swap_b32 %0, %1" : "+v"(a), "+v"(b));
}

#define MFMA16(a, b, c) __builtin_amdgcn_mfma_f32_16x16x32_bf16((a), (b), (c), 0, 0, 0)
#define MFMA32(a, b, c) __builtin_amdgcn_mfma_f32_32x32x16_bf16((a), (b), (c), 0, 0, 0)

// async global->LDS, 16B per lane. LDS dest is wave-uniform base + lane*16.
static __device__ __forceinline__ void gload16(const ushort* g, ushort* l) {
    __builtin_amdgcn_global_load_lds(
        (const __attribute__((address_space(1))) void*)g,
        (__attribute__((address_space(3))) void*)l, 16, 0, 0);
}

// XOR swizzle for [rows][128B] LDS tiles (16B granules).
static __device__ __forceinline__ int swz(int row, int col16) {
    return row * 128 + (((col16) * 16) ^ ((row & 7) << 4));
}

// ---------------------------------------------------------------------------
__global__ __launch_bounds__(256) void rope_tab(float* __restrict__ ct,
                                                float* __restrict__ st)
{
    const int idx = blockIdx.x * 256 + threadIdx.x;
    const int s = idx >> 5, fe = idx & 31;
    const float f = expf(-LN10K * (float)fe / 32.0f);
    const float a = (float)s * f;
    ct[idx] = cosf(a);
    st[idx] = sinf(a);
}

__global__ __launch_bounds__(256) void cvt_bf16(const float* __restrict__ in,
                                                ushort* __restrict__ out)
{
    const size_t i = ((size_t)blockIdx.x * 256 + threadIdx.x) * 8;
    const float4 a = *(const float4*)(in + i);
    const float4 b = *(const float4*)(in + i + 4);
    ushort4 lo = make_ushort4(f2bf(a.x), f2bf(a.y), f2bf(a.z), f2bf(a.w));
    ushort4 hi = make_ushort4(f2bf(b.x), f2bf(b.y), f2bf(b.z), f2bf(b.w));
    *(ushort4*)(out + i) = lo;
    *(ushort4*)(out + i + 4) = hi;
}

__global__ __launch_bounds__(256) void transpose_bf16(
    const float* __restrict__ in, ushort* __restrict__ out, int R, int C)
{
    __shared__ ushort t[32][33];
    const int n0 = blockIdx.x * 32, k0 = blockIdx.y * 32;
    const int x = threadIdx.x, y = threadIdx.y;
#pragma unroll
    for (int i = 0; i < 4; ++i)
        t[y + 8 * i][x] = f2bf(in[(size_t)(k0 + y + 8 * i) * C + n0 + x]);
    __syncthreads();
#pragma unroll
    for (int i = 0; i < 4; ++i)
        out[(size_t)(n0 + y + 8 * i) * R + k0 + x] = t[x][y + 8 * i];
}

// ---------------------------------------------------------------------------
// MFMA GEMM, m97-style (unchanged from round 10).
// ---------------------------------------------------------------------------
template <int MODE>
__global__ __launch_bounds__(256) void gemm_mfma(
    const ushort* __restrict__ A, const ushort* __restrict__ Bt,
    const float* __restrict__ bias, const float* __restrict__ ctab,
    const float* __restrict__ stab, ushort* __restrict__ o0,
    ushort* __restrict__ o1)
{
    __shared__ ushort Asm[128 * 64];   // [row][k] bf16, 128B rows, swizzled
    __shared__ ushort Bsm[128 * 64];

    const int tid = threadIdx.x;
    const int lane = tid & 63, w = tid >> 6;
    const int g = lane >> 4, c = lane & 15;
    const int mbase = blockIdx.y * 128;
    const int nbase = blockIdx.x * 128;
    const int wm = (w >> 1) * 64, wn = (w & 1) * 64;

    f32x4 acc[4][4];
#pragma unroll
    for (int mf = 0; mf < 4; ++mf)
#pragma unroll
        for (int nf = 0; nf < 4; ++nf)
            acc[mf][nf] = (f32x4){0.f, 0.f, 0.f, 0.f};

    const int sbase = w * 64 + lane;

    for (int k0 = 0; k0 < Kd; k0 += 64) {
#pragma unroll
        for (int j = 0; j < 4; ++j) {
            const int i = j * 256 + sbase;
            const int row = i >> 3, c16 = i & 7;
            const int kc = (c16 ^ (row & 7)) * 8;
            gload16(A + (size_t)(mbase + row) * Kd + k0 + kc,
                    &Asm[(size_t)(j * 256 + w * 64) * 8]);
            gload16(Bt + (size_t)(nbase + row) * Kd + k0 + kc,
                    &Bsm[(size_t)(j * 256 + w * 64) * 8]);
        }
        __syncthreads();

#pragma unroll
        for (int ks = 0; ks < 2; ++ks) {
            bf16x8 af[4], bfr[4];
#pragma unroll
            for (int mf = 0; mf < 4; ++mf) {
                const int row = wm + mf * 16 + c;
                af[mf] = *(const bf16x8*)((const char*)Asm + swz(row, ks * 4 + g));
            }
#pragma unroll
            for (int nf = 0; nf < 4; ++nf) {
                const int row = wn + nf * 16 + c;
                bfr[nf] = *(const bf16x8*)((const char*)Bsm + swz(row, ks * 4 + g));
            }
#pragma unroll
            for (int mf = 0; mf < 4; ++mf)
#pragma unroll
                for (int nf = 0; nf < 4; ++nf)
                    acc[mf][nf] = MFMA16(af[mf], bfr[nf], acc[mf][nf]);
        }
        __syncthreads();
    }

#pragma unroll
    for (int nf = 0; nf < 4; ++nf) {
        const int col = nbase + wn + nf * 16 + c;
        const float bs = bias[col];
        if (MODE == 0) {
            const int dh = col & 63, h = (col >> 6) & 15, isK = col >> 10;
            ushort* dst = isK ? o1 : o0;
            // Q: fold 1/sqrt(64) * log2(e) so attention exps are exp2
            const float sc = isK ? 1.0f : 0.18033688011112042f;
            const float* cr = ctab + (dh & 31);
            const float* sr = stab + (dh & 31);
#pragma unroll
            for (int mf = 0; mf < 4; ++mf) {
#pragma unroll
                for (int r = 0; r < 4; ++r) {
                    const int row = mbase + wm + mf * 16 + g * 4 + r;
                    const int s = row & 2047, b = row >> 11;
                    const float v = acc[mf][nf][r] + bs;
                    const float p = __shfl_xor(v, 1);
                    const float cs = cr[s * 32], sn = sr[s * 32];
                    const float ov = (c & 1) ? v * cs + p * sn
                                             : v * cs - p * sn;
                    dst[(((size_t)(b * Hn + h)) * Sn + s) * DHn + dh] =
                        f2bf(ov * sc);
                }
            }
        } else {
            const int h = col >> 6, dh = col & 63;
#pragma unroll
            for (int mf = 0; mf < 4; ++mf) {
#pragma unroll
                for (int r = 0; r < 4; ++r) {
                    const int row = mbase + wm + mf * 16 + g * 4 + r;
                    const int s = row & 2047, b = row >> 11;
                    const float v = acc[mf][nf][r] + bs;
                    o0[(((size_t)(b * Hn + h)) * DHn + dh) * Sn + s] = f2bf(v);
                }
            }
        }
    }
}

// ---------------------------------------------------------------------------
// MFMA flash attention, round 13: KV-SPLIT x2 via the `half` argument (1024
// kv rows, 16 iters per block) -> 1024 total blocks = 4/CU resident;
// double-buffered LDS (32 KB); __launch_bounds__(256,4) caps VGPR for 4
// waves/SIMD. Writes UNNORMALIZED numerators OP plus per-q l, m; ln_combine
// merges the halves. Core structure = round 12 (32x32 frags, swapped QK^T,
// permlane P-rebuild, exp2 domain, ones-column denominator).
// ---------------------------------------------------------------------------
__global__ __launch_bounds__(256, 4) void attn_mfma(
    const ushort* __restrict__ Qg, const ushort* __restrict__ Kg,
    const ushort* __restrict__ Vtg, float* __restrict__ OP,
    float* __restrict__ Lh, float* __restrict__ Mh, int half)
{
    __shared__ char Kt[2][8192];   // [64 kv][64 d] bf16, swizzled
    __shared__ char Vt[2][8192];   // [64 dh][64 kv] bf16, swizzled

    const int tid = threadIdx.x;
    const int lane = tid & 63, w = tid >> 6;
    const int r31 = lane & 31, hi = lane >> 5;
    const int bh = blockIdx.y;
    const int b = bh >> 4, h = bh & 15;
    const int q0 = blockIdx.x * 128 + w * 32;
    const int kvb = half * (Sn / 2);

    const ushort* qp = Qg + ((size_t)bh * Sn + q0 + r31) * DHn + hi * 8;
    bf16x8 qf[4];
#pragma unroll
    for (int kt = 0; kt < 4; ++kt)
        qf[kt] = *(const bf16x8*)(qp + kt * 16);

    const short one_bf = (short)0x3F80;
    const bf16x8 ones = {one_bf, one_bf, one_bf, one_bf,
                         one_bf, one_bf, one_bf, one_bf};

    const ushort* Kb = Kg + (size_t)bh * Sn * DHn;
    const ushort* Vb = Vtg + (size_t)bh * DHn * Sn;

    auto stage = [&](int buf, int kb) {
#pragma unroll
        for (int j = 0; j < 2; ++j) {
            const int i = j * 256 + w * 64 + lane;
            const int row = i >> 3, c16 = i & 7;
            const int kc = (c16 ^ (row & 7)) * 8;
            gload16(Kb + (size_t)(kb + row) * DHn + kc,
                    (ushort*)&Kt[buf][(j * 256 + w * 64) * 16]);
            gload16(Vb + (size_t)row * Sn + kb + kc,
                    (ushort*)&Vt[buf][(j * 256 + w * 64) * 16]);
        }
    };

    stage(0, kvb);

    f32x16 acc0, acc1, lacc;
#pragma unroll
    for (int i = 0; i < 16; ++i) { acc0[i] = 0.f; acc1[i] = 0.f; lacc[i] = 0.f; }
    float m = -1e30f;

    const int NT = (Sn / 2) / 64;   // 16
    for (int t = 0; t < NT; ++t) {
        const int cur = t & 1;

        __syncthreads();                       // drain tile-t DMAs + rally
        if (t + 1 < NT) stage(cur ^ 1, kvb + (t + 1) * 64);
        __builtin_amdgcn_sched_barrier(0);

        // ---- QK^T swapped: C[kv][q] for two 32-kv tiles ----
        f32x16 C0, C1;
#pragma unroll
        for (int i = 0; i < 16; ++i) { C0[i] = 0.f; C1[i] = 0.f; }
#pragma unroll
        for (int kt = 0; kt < 4; ++kt) {
            const bf16x8 ka = *(const bf16x8*)&Kt[cur][swz(r31, kt * 2 + hi)];
            C0 = MFMA32(ka, qf[kt], C0);
        }
#pragma unroll
        for (int kt = 0; kt < 4; ++kt) {
            const bf16x8 ka = *(const bf16x8*)&Kt[cur][swz(32 + r31, kt * 2 + hi)];
            C1 = MFMA32(ka, qf[kt], C1);
        }

        // ---- row max (q = r31) ----
        float mx[8];
#pragma unroll
        for (int i = 0; i < 8; ++i)
            mx[i] = fmaxf(fmaxf(C0[i], C0[i + 8]), fmaxf(C1[i], C1[i + 8]));
        mx[0] = fmaxf(mx[0], mx[4]); mx[1] = fmaxf(mx[1], mx[5]);
        mx[2] = fmaxf(mx[2], mx[6]); mx[3] = fmaxf(mx[3], mx[7]);
        float pmax = fmaxf(fmaxf(mx[0], mx[1]), fmaxf(mx[2], mx[3]));
        pmax = fmaxf(pmax, __shfl_xor(pmax, 32));

        // ---- defer-max rescale (rare; threshold 8*log2e) ----
        if (__any(pmax > m + 11.5f)) {
            const float mn = fmaxf(m, pmax);
            const float a = exp2f(m - mn);
            m = mn;
#pragma unroll
            for (int reg = 0; reg < 16; ++reg) {
                const int qr = (reg & 3) + 8 * (reg >> 2) + 4 * hi;
                const float ar = __shfl(a, qr);
                acc0[reg] *= ar;
                acc1[reg] *= ar;
                lacc[reg] *= ar;
            }
        }

        // ---- exp2 + pack + permlane -> PV A-frags ----
        bf16x8 paf[4];
#pragma unroll
        for (int tile = 0; tile < 2; ++tile) {
            const f32x16& C = tile ? C1 : C0;
            float e[16];
#pragma unroll
            for (int i = 0; i < 16; ++i) e[i] = exp2f(C[i] - m);
            uint p01 = cvtpk(e[0], e[1]),  p23 = cvtpk(e[2], e[3]);
            uint p45 = cvtpk(e[4], e[5]),  p67 = cvtpk(e[6], e[7]);
            uint p89 = cvtpk(e[8], e[9]),  pab = cvtpk(e[10], e[11]);
            uint pcd = cvtpk(e[12], e[13]), pef = cvtpk(e[14], e[15]);
            plswap(p01, p45); plswap(p23, p67);
            plswap(p89, pcd); plswap(pab, pef);
            uint4 f0 = {p01, p23, p45, p67};
            uint4 f1 = {p89, pab, pcd, pef};
            paf[tile * 2 + 0] = *(const bf16x8*)&f0;
            paf[tile * 2 + 1] = *(const bf16x8*)&f1;
        }

        // ---- PV + denominator ----
#pragma unroll
        for (int kf = 0; kf < 4; ++kf) {
            const bf16x8 v0 = *(const bf16x8*)&Vt[cur][swz(r31, kf * 2 + hi)];
            acc0 = MFMA32(paf[kf], v0, acc0);
        }
#pragma unroll
        for (int kf = 0; kf < 4; ++kf) {
            const bf16x8 v1 = *(const bf16x8*)&Vt[cur][swz(32 + r31, kf * 2 + hi)];
            acc1 = MFMA32(paf[kf], v1, acc1);
        }
#pragma unroll
        for (int kf = 0; kf < 4; ++kf)
            lacc = MFMA32(paf[kf], ones, lacc);
    }

    // ---- epilogue: unnormalized numerators + (l, m) for the combine ----
#pragma unroll
    for (int reg = 0; reg < 16; ++reg) {
        const int qr = (reg & 3) + 8 * (reg >> 2) + 4 * hi;
        const int qs = q0 + qr;
        float* dst = &OP[((size_t)b * Sn + qs) * Dn + h * DHn + r31];
        dst[0]  = acc0[reg];
        dst[32] = acc1[reg];
    }
    if (r31 == 0) {
#pragma unroll
        for (int reg = 0; reg < 16; ++reg) {
            const int qr = (reg & 3) + 8 * (reg >> 2) + 4 * hi;
            Lh[(size_t)bh * Sn + q0 + qr] = lacc[reg];
        }
    }
    if (hi == 0)
        Mh[(size_t)bh * Sn + q0 + r31] = m;
}

// ---------------------------------------------------------------------------
// Combine (flash merge of the two KV halves) + LayerNorm; f32 output.
// ---------------------------------------------------------------------------
__global__ __launch_bounds__(256) void ln_combine(
    const float* __restrict__ OP0, const float* __restrict__ OP1,
    const float* __restrict__ L0, const float* __restrict__ M0,
    const float* __restrict__ L1, const float* __restrict__ M1,
    const float* __restrict__ gamma, const float* __restrict__ beta,
    float* __restrict__ out)
{
    const int row = blockIdx.x;          // b*Sn + s
    const int b = row >> 11, s = row & 2047;
    const int tid = threadIdx.x;
    const int d0 = tid * 4;
    const int h = d0 >> 6;
    const size_t idx = (size_t)(b * Hn + h) * Sn + s;

    const float l0 = L0[idx], m0 = M0[idx];
    const float l1 = L1[idx], m1 = M1[idx];
    const float mm = fmaxf(m0, m1);
    const float w0 = exp2f(m0 - mm), w1 = exp2f(m1 - mm);
    const float inv = 1.0f / (l0 * w0 + l1 * w1);

    const float4 o0 = *(const float4*)&OP0[(size_t)row * Dn + d0];
    const float4 o1 = *(const float4*)&OP1[(size_t)row * Dn + d0];
    float4 x;
    x.x = (o0.x * w0 + o1.x * w1) * inv;
    x.y = (o0.y * w0 + o1.y * w1) * inv;
    x.z = (o0.z * w0 + o1.z * w1) * inv;
    x.w = (o0.w * w0 + o1.w * w1) * inv;

    float sum = x.x + x.y + x.z + x.w;
    float sq = x.x * x.x + x.y * x.y + x.z * x.z + x.w * x.w;
    for (int off = 32; off; off >>= 1) {
        sum += __shfl_xor(sum, off);
        sq += __shfl_xor(sq, off);
    }
    __shared__ float red[8];
    const int lane = tid & 63, wave = tid >> 6;
    if (lane == 0) { red[wave] = sum; red[wave + 4] = sq; }
    __syncthreads();
    if (tid == 0) {
        red[0] = red[0] + red[1] + red[2] + red[3];
        red[4] = red[4] + red[5] + red[6] + red[7];
    }
    __syncthreads();
    sum = red[0]; sq = red[4];
    const float mu = sum * (1.0f / Dn);
    const float var = sq * (1.0f / Dn) - mu * mu;
    const float rs = rsqrtf(var + 1e-5f);

    const float4 gv = *(const float4*)&gamma[d0];
    const float4 bv = *(const float4*)&beta[d0];
    float4 ov;
    ov.x = (x.x - mu) * rs * gv.x + bv.x;
    ov.y = (x.y - mu) * rs * gv.y + bv.y;
    ov.z = (x.z - mu) * rs * gv.z + bv.z;
    ov.w = (x.w - mu) * rs * gv.w + bv.w;
    *(float4*)&out[(size_t)row * Dn + d0] = ov;
}

extern "C" void kernel_launch(void* const* d_in, const int* in_sizes, int n_in,
                              void* d_out, int out_size, void* d_ws, size_t ws_size,
                              hipStream_t stream)
{
    const float* x_qk = (const float*)d_in[0];
    const float* x_v  = (const float*)d_in[1];
    const float* W_qk = (const float*)d_in[2];
    const float* b_qk = (const float*)d_in[3];
    const float* W_v  = (const float*)d_in[4];
    const float* b_v  = (const float*)d_in[5];
    const float* g    = (const float*)d_in[6];
    const float* be   = (const float*)d_in[7];

    char* ws = (char*)d_ws;
    ushort* Qw    = (ushort*)(ws);                  //  8 MB bf16 (b,h,s,dh)
    ushort* Kw    = (ushort*)(ws + (8u  << 20));    //  8 MB bf16 (b,h,s,dh)
    ushort* Vtw   = (ushort*)(ws + (16u << 20));    //  8 MB bf16 (b,h,dh,s)
    float*  OP0   = (float*) (ws + (24u << 20));    // 16 MB f32 numerators half0
    ushort* xqkB  = (ushort*)(ws + (40u << 20));    //  8 MB bf16 [M][K]
    ushort* xvB   = (ushort*)(ws + (48u << 20));    //  8 MB bf16 [M][K]
    float*  OP1   = (float*) (ws + (40u << 20));    // 16 MB, overlays xqkB+xvB (dead post-GEMM)
    ushort* WqkT  = (ushort*)(ws + (56u << 20));    //  4 MB bf16 [2048][1024]
    ushort* WvT   = (ushort*)(ws + (60u << 20));    //  2 MB bf16 [1024][1024]
    float*  L0    = (float*) (ws + (56u << 20));    // 256 KB (bh,q) — overlays WqkT post-GEMM1
    float*  M0    = L0 + 65536;
    float*  L1    = M0 + 65536;
    float*  M1    = L1 + 65536;
    float*  ctab  = (float*) (ws + (62u << 20));    // 256 KB
    float*  stab  = (float*) (ws + (62u << 20) + (256u << 10));

    rope_tab<<<256, 256, 0, stream>>>(ctab, stab);
    cvt_bf16<<<2048, 256, 0, stream>>>(x_qk, xqkB);
    cvt_bf16<<<2048, 256, 0, stream>>>(x_v, xvB);
    transpose_bf16<<<dim3(64, 32), dim3(32, 8), 0, stream>>>(W_qk, WqkT, Kd, 2048);
    transpose_bf16<<<dim3(32, 32), dim3(32, 8), 0, stream>>>(W_v, WvT, Kd, 1024);

    gemm_mfma<0><<<dim3(16, 32), 256, 0, stream>>>(
        xqkB, WqkT, b_qk, ctab, stab, Qw, Kw);
    gemm_mfma<1><<<dim3(8, 32), 256, 0, stream>>>(
        xvB, WvT, b_v, ctab, stab, Vtw, nullptr);

    // KV-split attention: two 512-block launches (halves 0 and 1); they
    // queue back-to-back so CU residency doubles vs one 512-block launch.
    attn_mfma<<<dim3(16, 32), 256, 0, stream>>>(Qw, Kw, Vtw, OP0, L0, M0, 0);
    attn_mfma<<<dim3(16, 32), 256, 0, stream>>>(Qw, Kw, Vtw, OP1, L1, M1, 1);

    ln_combine<<<Bn * Sn, 256, 0, stream>>>(OP0, OP1, L0, M0, L1, M1,
                                            g, be, (float*)d_out);
}

// Round 14
// 181.639 us; speedup vs baseline: 1.1359x; 1.1359x over previous
//
#include <hip/hip_runtime.h>
#include <hip/hip_bf16.h>

// B=2, S=2048, D=1024, H=16, DH=64. f32 in/out; bf16 intermediates for MFMA.
#define Bn 2
#define Sn 2048
#define Dn 1024
#define Hn 16
#define DHn 64
#define Kd 1024
#define Mn (Bn * Sn)
#define LN10K 9.210340371976184f

typedef __attribute__((ext_vector_type(8))) short bf16x8;   // MFMA A/B frag
typedef __attribute__((ext_vector_type(4))) float f32x4;    // 16x16 C/D frag
typedef __attribute__((ext_vector_type(16))) float f32x16;  // 32x32 C/D frag

static __device__ __forceinline__ ushort f2bf(float f) {
    uint u = __float_as_uint(f);
    u += 0x7fff + ((u >> 16) & 1);   // round-nearest-even
    return (ushort)(u >> 16);
}
// packed f32x2 -> bf16x2 (RNE), lo = a, hi = b
static __device__ __forceinline__ uint cvtpk(float a, float b) {
    uint r;
    asm("v_cvt_pk_bf16_f32 %0, %1, %2" : "=v"(r) : "v"(a), "v"(b));
    return r;
}
// swap a.hi32lanes <-> b.lo32lanes
static __device__ __forceinline__ void plswap(uint& a, uint& b) {
    asm volatile("v_permlane32_swap_b32 %0, %1" : "+v"(a), "+v"(b));
}

#define MFMA16(a, b, c) __builtin_amdgcn_mfma_f32_16x16x32_bf16((a), (b), (c), 0, 0, 0)
#define MFMA32(a, b, c) __builtin_amdgcn_mfma_f32_32x32x16_bf16((a), (b), (c), 0, 0, 0)

// async global->LDS, 16B per lane. LDS dest is wave-uniform base + lane*16.
static __device__ __forceinline__ void gload16(const ushort* g, ushort* l) {
    __builtin_amdgcn_global_load_lds(
        (const __attribute__((address_space(1))) void*)g,
        (__attribute__((address_space(3))) void*)l, 16, 0, 0);
}

// XOR swizzle for [rows][128B] LDS tiles (16B granules).
static __device__ __forceinline__ int swz(int row, int col16) {
    return row * 128 + (((col16) * 16) ^ ((row & 7) << 4));
}

// ---------------------------------------------------------------------------
__global__ __launch_bounds__(256) void rope_tab(float* __restrict__ ct,
                                                float* __restrict__ st)
{
    const int idx = blockIdx.x * 256 + threadIdx.x;
    const int s = idx >> 5, fe = idx & 31;
    const float f = expf(-LN10K * (float)fe / 32.0f);
    const float a = (float)s * f;
    ct[idx] = cosf(a);
    st[idx] = sinf(a);
}

__global__ __launch_bounds__(256) void cvt_bf16(const float* __restrict__ in,
                                                ushort* __restrict__ out)
{
    const size_t i = ((size_t)blockIdx.x * 256 + threadIdx.x) * 8;
    const float4 a = *(const float4*)(in + i);
    const float4 b = *(const float4*)(in + i + 4);
    ushort4 lo = make_ushort4(f2bf(a.x), f2bf(a.y), f2bf(a.z), f2bf(a.w));
    ushort4 hi = make_ushort4(f2bf(b.x), f2bf(b.y), f2bf(b.z), f2bf(b.w));
    *(ushort4*)(out + i) = lo;
    *(ushort4*)(out + i + 4) = hi;
}

__global__ __launch_bounds__(256) void transpose_bf16(
    const float* __restrict__ in, ushort* __restrict__ out, int R, int C)
{
    __shared__ ushort t[32][33];
    const int n0 = blockIdx.x * 32, k0 = blockIdx.y * 32;
    const int x = threadIdx.x, y = threadIdx.y;
#pragma unroll
    for (int i = 0; i < 4; ++i)
        t[y + 8 * i][x] = f2bf(in[(size_t)(k0 + y + 8 * i) * C + n0 + x]);
    __syncthreads();
#pragma unroll
    for (int i = 0; i < 4; ++i)
        out[(size_t)(n0 + y + 8 * i) * R + k0 + x] = t[x][y + 8 * i];
}

// ---------------------------------------------------------------------------
// MFMA GEMM, m97-style (unchanged from round 10).
// ---------------------------------------------------------------------------
template <int MODE>
__global__ __launch_bounds__(256) void gemm_mfma(
    const ushort* __restrict__ A, const ushort* __restrict__ Bt,
    const float* __restrict__ bias, const float* __restrict__ ctab,
    const float* __restrict__ stab, ushort* __restrict__ o0,
    ushort* __restrict__ o1)
{
    __shared__ ushort Asm[128 * 64];   // [row][k] bf16, 128B rows, swizzled
    __shared__ ushort Bsm[128 * 64];

    const int tid = threadIdx.x;
    const int lane = tid & 63, w = tid >> 6;
    const int g = lane >> 4, c = lane & 15;
    const int mbase = blockIdx.y * 128;
    const int nbase = blockIdx.x * 128;
    const int wm = (w >> 1) * 64, wn = (w & 1) * 64;

    f32x4 acc[4][4];
#pragma unroll
    for (int mf = 0; mf < 4; ++mf)
#pragma unroll
        for (int nf = 0; nf < 4; ++nf)
            acc[mf][nf] = (f32x4){0.f, 0.f, 0.f, 0.f};

    const int sbase = w * 64 + lane;

    for (int k0 = 0; k0 < Kd; k0 += 64) {
#pragma unroll
        for (int j = 0; j < 4; ++j) {
            const int i = j * 256 + sbase;
            const int row = i >> 3, c16 = i & 7;
            const int kc = (c16 ^ (row & 7)) * 8;
            gload16(A + (size_t)(mbase + row) * Kd + k0 + kc,
                    &Asm[(size_t)(j * 256 + w * 64) * 8]);
            gload16(Bt + (size_t)(nbase + row) * Kd + k0 + kc,
                    &Bsm[(size_t)(j * 256 + w * 64) * 8]);
        }
        __syncthreads();

#pragma unroll
        for (int ks = 0; ks < 2; ++ks) {
            bf16x8 af[4], bfr[4];
#pragma unroll
            for (int mf = 0; mf < 4; ++mf) {
                const int row = wm + mf * 16 + c;
                af[mf] = *(const bf16x8*)((const char*)Asm + swz(row, ks * 4 + g));
            }
#pragma unroll
            for (int nf = 0; nf < 4; ++nf) {
                const int row = wn + nf * 16 + c;
                bfr[nf] = *(const bf16x8*)((const char*)Bsm + swz(row, ks * 4 + g));
            }
#pragma unroll
            for (int mf = 0; mf < 4; ++mf)
#pragma unroll
                for (int nf = 0; nf < 4; ++nf)
                    acc[mf][nf] = MFMA16(af[mf], bfr[nf], acc[mf][nf]);
        }
        __syncthreads();
    }

#pragma unroll
    for (int nf = 0; nf < 4; ++nf) {
        const int col = nbase + wn + nf * 16 + c;
        const float bs = bias[col];
        if (MODE == 0) {
            const int dh = col & 63, h = (col >> 6) & 15, isK = col >> 10;
            ushort* dst = isK ? o1 : o0;
            // Q: fold 1/sqrt(64) * log2(e) so attention exps are exp2
            const float sc = isK ? 1.0f : 0.18033688011112042f;
            const float* cr = ctab + (dh & 31);
            const float* sr = stab + (dh & 31);
#pragma unroll
            for (int mf = 0; mf < 4; ++mf) {
#pragma unroll
                for (int r = 0; r < 4; ++r) {
                    const int row = mbase + wm + mf * 16 + g * 4 + r;
                    const int s = row & 2047, b = row >> 11;
                    const float v = acc[mf][nf][r] + bs;
                    const float p = __shfl_xor(v, 1);
                    const float cs = cr[s * 32], sn = sr[s * 32];
                    const float ov = (c & 1) ? v * cs + p * sn
                                             : v * cs - p * sn;
                    dst[(((size_t)(b * Hn + h)) * Sn + s) * DHn + dh] =
                        f2bf(ov * sc);
                }
            }
        } else {
            const int h = col >> 6, dh = col & 63;
#pragma unroll
            for (int mf = 0; mf < 4; ++mf) {
#pragma unroll
                for (int r = 0; r < 4; ++r) {
                    const int row = mbase + wm + mf * 16 + g * 4 + r;
                    const int s = row & 2047, b = row >> 11;
                    const float v = acc[mf][nf][r] + bs;
                    o0[(((size_t)(b * Hn + h)) * DHn + dh) * Sn + s] = f2bf(v);
                }
            }
        }
    }
}

// ---------------------------------------------------------------------------
// MFMA flash attention, round 14: KV-split x2 in ONE launch (gridDim.z = 2,
// per-half outputs selected by blockIdx.z) -> 1024 resident blocks = 4/CU.
// Double-buffered LDS (32 KB), __launch_bounds__(256,4). Writes UNNORMALIZED
// numerators + per-q (l, m); ln_combine merges. Core = round 12 structure.
// ---------------------------------------------------------------------------
__global__ __launch_bounds__(256, 4) void attn_mfma(
    const ushort* __restrict__ Qg, const ushort* __restrict__ Kg,
    const ushort* __restrict__ Vtg, float* __restrict__ OP0,
    float* __restrict__ OP1, float* __restrict__ L0, float* __restrict__ M0,
    float* __restrict__ L1, float* __restrict__ M1)
{
    __shared__ char Kt[2][8192];   // [64 kv][64 d] bf16, swizzled
    __shared__ char Vt[2][8192];   // [64 dh][64 kv] bf16, swizzled

    const int tid = threadIdx.x;
    const int lane = tid & 63, w = tid >> 6;
    const int r31 = lane & 31, hi = lane >> 5;
    const int bh = blockIdx.y;
    const int b = bh >> 4, h = bh & 15;
    const int q0 = blockIdx.x * 128 + w * 32;
    const int half = blockIdx.z;
    const int kvb = half * (Sn / 2);

    float* __restrict__ OP = half ? OP1 : OP0;
    float* __restrict__ Lh = half ? L1 : L0;
    float* __restrict__ Mh = half ? M1 : M0;

    const ushort* qp = Qg + ((size_t)bh * Sn + q0 + r31) * DHn + hi * 8;
    bf16x8 qf[4];
#pragma unroll
    for (int kt = 0; kt < 4; ++kt)
        qf[kt] = *(const bf16x8*)(qp + kt * 16);

    const short one_bf = (short)0x3F80;
    const bf16x8 ones = {one_bf, one_bf, one_bf, one_bf,
                         one_bf, one_bf, one_bf, one_bf};

    const ushort* Kb = Kg + (size_t)bh * Sn * DHn;
    const ushort* Vb = Vtg + (size_t)bh * DHn * Sn;

    auto stage = [&](int buf, int kb) {
#pragma unroll
        for (int j = 0; j < 2; ++j) {
            const int i = j * 256 + w * 64 + lane;
            const int row = i >> 3, c16 = i & 7;
            const int kc = (c16 ^ (row & 7)) * 8;
            gload16(Kb + (size_t)(kb + row) * DHn + kc,
                    (ushort*)&Kt[buf][(j * 256 + w * 64) * 16]);
            gload16(Vb + (size_t)row * Sn + kb + kc,
                    (ushort*)&Vt[buf][(j * 256 + w * 64) * 16]);
        }
    };

    stage(0, kvb);

    f32x16 acc0, acc1, lacc;
#pragma unroll
    for (int i = 0; i < 16; ++i) { acc0[i] = 0.f; acc1[i] = 0.f; lacc[i] = 0.f; }
    float m = -1e30f;

    const int NT = (Sn / 2) / 64;   // 16
    for (int t = 0; t < NT; ++t) {
        const int cur = t & 1;

        __syncthreads();                       // drain tile-t DMAs + rally
        if (t + 1 < NT) stage(cur ^ 1, kvb + (t + 1) * 64);
        __builtin_amdgcn_sched_barrier(0);

        // ---- QK^T swapped: C[kv][q] for two 32-kv tiles ----
        f32x16 C0, C1;
#pragma unroll
        for (int i = 0; i < 16; ++i) { C0[i] = 0.f; C1[i] = 0.f; }
#pragma unroll
        for (int kt = 0; kt < 4; ++kt) {
            const bf16x8 ka = *(const bf16x8*)&Kt[cur][swz(r31, kt * 2 + hi)];
            C0 = MFMA32(ka, qf[kt], C0);
        }
#pragma unroll
        for (int kt = 0; kt < 4; ++kt) {
            const bf16x8 ka = *(const bf16x8*)&Kt[cur][swz(32 + r31, kt * 2 + hi)];
            C1 = MFMA32(ka, qf[kt], C1);
        }

        // ---- row max (q = r31) ----
        float mx[8];
#pragma unroll
        for (int i = 0; i < 8; ++i)
            mx[i] = fmaxf(fmaxf(C0[i], C0[i + 8]), fmaxf(C1[i], C1[i + 8]));
        mx[0] = fmaxf(mx[0], mx[4]); mx[1] = fmaxf(mx[1], mx[5]);
        mx[2] = fmaxf(mx[2], mx[6]); mx[3] = fmaxf(mx[3], mx[7]);
        float pmax = fmaxf(fmaxf(mx[0], mx[1]), fmaxf(mx[2], mx[3]));
        pmax = fmaxf(pmax, __shfl_xor(pmax, 32));

        // ---- defer-max rescale (rare; threshold 8*log2e) ----
        if (__any(pmax > m + 11.5f)) {
            const float mn = fmaxf(m, pmax);
            const float a = exp2f(m - mn);
            m = mn;
#pragma unroll
            for (int reg = 0; reg < 16; ++reg) {
                const int qr = (reg & 3) + 8 * (reg >> 2) + 4 * hi;
                const float ar = __shfl(a, qr);
                acc0[reg] *= ar;
                acc1[reg] *= ar;
                lacc[reg] *= ar;
            }
        }

        // ---- exp2 + pack + permlane -> PV A-frags ----
        bf16x8 paf[4];
#pragma unroll
        for (int tile = 0; tile < 2; ++tile) {
            const f32x16& C = tile ? C1 : C0;
            float e[16];
#pragma unroll
            for (int i = 0; i < 16; ++i) e[i] = exp2f(C[i] - m);
            uint p01 = cvtpk(e[0], e[1]),  p23 = cvtpk(e[2], e[3]);
            uint p45 = cvtpk(e[4], e[5]),  p67 = cvtpk(e[6], e[7]);
            uint p89 = cvtpk(e[8], e[9]),  pab = cvtpk(e[10], e[11]);
            uint pcd = cvtpk(e[12], e[13]), pef = cvtpk(e[14], e[15]);
            plswap(p01, p45); plswap(p23, p67);
            plswap(p89, pcd); plswap(pab, pef);
            uint4 f0 = {p01, p23, p45, p67};
            uint4 f1 = {p89, pab, pcd, pef};
            paf[tile * 2 + 0] = *(const bf16x8*)&f0;
            paf[tile * 2 + 1] = *(const bf16x8*)&f1;
        }

        // ---- PV + denominator ----
#pragma unroll
        for (int kf = 0; kf < 4; ++kf) {
            const bf16x8 v0 = *(const bf16x8*)&Vt[cur][swz(r31, kf * 2 + hi)];
            acc0 = MFMA32(paf[kf], v0, acc0);
        }
#pragma unroll
        for (int kf = 0; kf < 4; ++kf) {
            const bf16x8 v1 = *(const bf16x8*)&Vt[cur][swz(32 + r31, kf * 2 + hi)];
            acc1 = MFMA32(paf[kf], v1, acc1);
        }
#pragma unroll
        for (int kf = 0; kf < 4; ++kf)
            lacc = MFMA32(paf[kf], ones, lacc);
    }

    // ---- epilogue: unnormalized numerators + (l, m) for the combine ----
#pragma unroll
    for (int reg = 0; reg < 16; ++reg) {
        const int qr = (reg & 3) + 8 * (reg >> 2) + 4 * hi;
        const int qs = q0 + qr;
        float* dst = &OP[((size_t)b * Sn + qs) * Dn + h * DHn + r31];
        dst[0]  = acc0[reg];
        dst[32] = acc1[reg];
    }
    if (r31 == 0) {
#pragma unroll
        for (int reg = 0; reg < 16; ++reg) {
            const int qr = (reg & 3) + 8 * (reg >> 2) + 4 * hi;
            Lh[(size_t)bh * Sn + q0 + qr] = lacc[reg];
        }
    }
    if (hi == 0)
        Mh[(size_t)bh * Sn + q0 + r31] = m;
}

// ---------------------------------------------------------------------------
// Combine (flash merge of the two KV halves) + LayerNorm; f32 output.
// ---------------------------------------------------------------------------
__global__ __launch_bounds__(256) void ln_combine(
    const float* __restrict__ OP0, const float* __restrict__ OP1,
    const float* __restrict__ L0, const float* __restrict__ M0,
    const float* __restrict__ L1, const float* __restrict__ M1,
    const float* __restrict__ gamma, const float* __restrict__ beta,
    float* __restrict__ out)
{
    const int row = blockIdx.x;          // b*Sn + s
    const int b = row >> 11, s = row & 2047;
    const int tid = threadIdx.x;
    const int d0 = tid * 4;
    const int h = d0 >> 6;
    const size_t idx = (size_t)(b * Hn + h) * Sn + s;

    const float l0 = L0[idx], m0 = M0[idx];
    const float l1 = L1[idx], m1 = M1[idx];
    const float mm = fmaxf(m0, m1);
    const float w0 = exp2f(m0 - mm), w1 = exp2f(m1 - mm);
    const float inv = 1.0f / (l0 * w0 + l1 * w1);

    const float4 o0 = *(const float4*)&OP0[(size_t)row * Dn + d0];
    const float4 o1 = *(const float4*)&OP1[(size_t)row * Dn + d0];
    float4 x;
    x.x = (o0.x * w0 + o1.x * w1) * inv;
    x.y = (o0.y * w0 + o1.y * w1) * inv;
    x.z = (o0.z * w0 + o1.z * w1) * inv;
    x.w = (o0.w * w0 + o1.w * w1) * inv;

    float sum = x.x + x.y + x.z + x.w;
    float sq = x.x * x.x + x.y * x.y + x.z * x.z + x.w * x.w;
    for (int off = 32; off; off >>= 1) {
        sum += __shfl_xor(sum, off);
        sq += __shfl_xor(sq, off);
    }
    __shared__ float red[8];
    const int lane = tid & 63, wave = tid >> 6;
    if (lane == 0) { red[wave] = sum; red[wave + 4] = sq; }
    __syncthreads();
    if (tid == 0) {
        red[0] = red[0] + red[1] + red[2] + red[3];
        red[4] = red[4] + red[5] + red[6] + red[7];
    }
    __syncthreads();
    sum = red[0]; sq = red[4];
    const float mu = sum * (1.0f / Dn);
    const float var = sq * (1.0f / Dn) - mu * mu;
    const float rs = rsqrtf(var + 1e-5f);

    const float4 gv = *(const float4*)&gamma[d0];
    const float4 bv = *(const float4*)&beta[d0];
    float4 ov;
    ov.x = (x.x - mu) * rs * gv.x + bv.x;
    ov.y = (x.y - mu) * rs * gv.y + bv.y;
    ov.z = (x.z - mu) * rs * gv.z + bv.z;
    ov.w = (x.w - mu) * rs * gv.w + bv.w;
    *(float4*)&out[(size_t)row * Dn + d0] = ov;
}

extern "C" void kernel_launch(void* const* d_in, const int* in_sizes, int n_in,
                              void* d_out, int out_size, void* d_ws, size_t ws_size,
                              hipStream_t stream)
{
    const float* x_qk = (const float*)d_in[0];
    const float* x_v  = (const float*)d_in[1];
    const float* W_qk = (const float*)d_in[2];
    const float* b_qk = (const float*)d_in[3];
    const float* W_v  = (const float*)d_in[4];
    const float* b_v  = (const float*)d_in[5];
    const float* g    = (const float*)d_in[6];
    const float* be   = (const float*)d_in[7];

    char* ws = (char*)d_ws;
    ushort* Qw    = (ushort*)(ws);                  //  8 MB bf16 (b,h,s,dh)
    ushort* Kw    = (ushort*)(ws + (8u  << 20));    //  8 MB bf16 (b,h,s,dh)
    ushort* Vtw   = (ushort*)(ws + (16u << 20));    //  8 MB bf16 (b,h,dh,s)
    float*  OP0   = (float*) (ws + (24u << 20));    // 16 MB f32 numerators half0
    ushort* xqkB  = (ushort*)(ws + (40u << 20));    //  8 MB bf16 [M][K]
    ushort* xvB   = (ushort*)(ws + (48u << 20));    //  8 MB bf16 [M][K]
    float*  OP1   = (float*) (ws + (40u << 20));    // 16 MB, overlays xqkB+xvB (dead post-GEMM)
    ushort* WqkT  = (ushort*)(ws + (56u << 20));    //  4 MB bf16 [2048][1024]
    ushort* WvT   = (ushort*)(ws + (60u << 20));    //  2 MB bf16 [1024][1024]
    float*  L0    = (float*) (ws + (56u << 20));    // 256 KB (bh,q) — overlays WqkT post-GEMM1
    float*  M0    = L0 + 65536;
    float*  L1    = M0 + 65536;
    float*  M1    = L1 + 65536;
    float*  ctab  = (float*) (ws + (62u << 20));    // 256 KB
    float*  stab  = (float*) (ws + (62u << 20) + (256u << 10));

    rope_tab<<<256, 256, 0, stream>>>(ctab, stab);
    cvt_bf16<<<2048, 256, 0, stream>>>(x_qk, xqkB);
    cvt_bf16<<<2048, 256, 0, stream>>>(x_v, xvB);
    transpose_bf16<<<dim3(64, 32), dim3(32, 8), 0, stream>>>(W_qk, WqkT, Kd, 2048);
    transpose_bf16<<<dim3(32, 32), dim3(32, 8), 0, stream>>>(W_v, WvT, Kd, 1024);

    gemm_mfma<0><<<dim3(16, 32), 256, 0, stream>>>(
        xqkB, WqkT, b_qk, ctab, stab, Qw, Kw);
    gemm_mfma<1><<<dim3(8, 32), 256, 0, stream>>>(
        xvB, WvT, b_v, ctab, stab, Vtw, nullptr);

    // KV-split attention: ONE launch, gridDim.z = 2 -> 1024 resident blocks.
    attn_mfma<<<dim3(16, 32, 2), 256, 0, stream>>>(
        Qw, Kw, Vtw, OP0, OP1, L0, M0, L1, M1);

    ln_combine<<<Bn * Sn, 256, 0, stream>>>(OP0, OP1, L0, M0, L1, M1,
                                            g, be, (float*)d_out);
}

// Round 15
// 137.378 us; speedup vs baseline: 1.5018x; 1.3222x over previous
//
#include <hip/hip_runtime.h>
#include <hip/hip_bf16.h>

// B=2, S=2048, D=1024, H=16, DH=64. f32 in/out; bf16 intermediates for MFMA.
#define Bn 2
#define Sn 2048
#define Dn 1024
#define Hn 16
#define DHn 64
#define Kd 1024
#define Mn (Bn * Sn)
#define LN10K 9.210340371976184f

typedef __attribute__((ext_vector_type(8))) short bf16x8;   // MFMA A/B frag
typedef __attribute__((ext_vector_type(4))) float f32x4;    // 16x16 C/D frag
typedef __attribute__((ext_vector_type(16))) float f32x16;  // 32x32 C/D frag

static __device__ __forceinline__ ushort f2bf(float f) {
    uint u = __float_as_uint(f);
    u += 0x7fff + ((u >> 16) & 1);   // round-nearest-even
    return (ushort)(u >> 16);
}
// packed f32x2 -> bf16x2 (RNE), lo = a, hi = b
static __device__ __forceinline__ uint cvtpk(float a, float b) {
    uint r;
    asm("v_cvt_pk_bf16_f32 %0, %1, %2" : "=v"(r) : "v"(a), "v"(b));
    return r;
}
// swap a.hi32lanes <-> b.lo32lanes
static __device__ __forceinline__ void plswap(uint& a, uint& b) {
    asm volatile("v_permlane32_swap_b32 %0, %1" : "+v"(a), "+v"(b));
}

#define MFMA16(a, b, c) __builtin_amdgcn_mfma_f32_16x16x32_bf16((a), (b), (c), 0, 0, 0)
#define MFMA32(a, b, c) __builtin_amdgcn_mfma_f32_32x32x16_bf16((a), (b), (c), 0, 0, 0)

// async global->LDS, 16B per lane. LDS dest is wave-uniform base + lane*16.
static __device__ __forceinline__ void gload16(const ushort* g, ushort* l) {
    __builtin_amdgcn_global_load_lds(
        (const __attribute__((address_space(1))) void*)g,
        (__attribute__((address_space(3))) void*)l, 16, 0, 0);
}

// XOR swizzle for [rows][128B] LDS tiles (16B granules).
static __device__ __forceinline__ int swz(int row, int col16) {
    return row * 128 + (((col16) * 16) ^ ((row & 7) << 4));
}

// ---------------------------------------------------------------------------
// Fused prep: [0,2048) cvt x_qk; [2048,4096) cvt x_v; [4096,6144) transpose
// W_qk; [6144,7168) transpose W_v; [7168,7424) RoPE table. Block-uniform
// branches; one launch replaces five.
// ---------------------------------------------------------------------------
__global__ __launch_bounds__(256) void prep(
    const float* __restrict__ x_qk, const float* __restrict__ x_v,
    const float* __restrict__ W_qk, const float* __restrict__ W_v,
    ushort* __restrict__ xqkB, ushort* __restrict__ xvB,
    ushort* __restrict__ WqkT, ushort* __restrict__ WvT,
    float* __restrict__ ct, float* __restrict__ st)
{
    __shared__ ushort tle[32][33];
    const int blk = blockIdx.x;
    const int tid = threadIdx.x;

    if (blk < 4096) {
        // f32 -> bf16 elementwise, 8 per thread
        const float* in = (blk < 2048) ? x_qk : x_v;
        ushort* out = (blk < 2048) ? xqkB : xvB;
        const int lb = (blk < 2048) ? blk : blk - 2048;
        const size_t i = ((size_t)lb * 256 + tid) * 8;
        const float4 a = *(const float4*)(in + i);
        const float4 b = *(const float4*)(in + i + 4);
        *(ushort4*)(out + i) =
            make_ushort4(f2bf(a.x), f2bf(a.y), f2bf(a.z), f2bf(a.w));
        *(ushort4*)(out + i + 4) =
            make_ushort4(f2bf(b.x), f2bf(b.y), f2bf(b.z), f2bf(b.w));
    } else if (blk < 7168) {
        // transpose+convert W [K][C] f32 -> [C][K] bf16, 32x32 tiles
        const bool isQK = blk < 6144;
        const int t = isQK ? blk - 4096 : blk - 6144;
        const int C = isQK ? 2048 : 1024;
        const float* in = isQK ? W_qk : W_v;
        ushort* out = isQK ? WqkT : WvT;
        const int n0 = (isQK ? (t & 63) : (t & 31)) * 32;
        const int k0 = (isQK ? (t >> 6) : (t >> 5)) * 32;
        const int x = tid & 31, y = tid >> 5;   // 32 x 8
#pragma unroll
        for (int i = 0; i < 4; ++i)
            tle[y + 8 * i][x] = f2bf(in[(size_t)(k0 + y + 8 * i) * C + n0 + x]);
        __syncthreads();
#pragma unroll
        for (int i = 0; i < 4; ++i)
            out[(size_t)(n0 + y + 8 * i) * Kd + k0 + x] = tle[x][y + 8 * i];
    } else {
        // RoPE table: ct/st[s][fe]
        const int idx = (blk - 7168) * 256 + tid;
        const int s = idx >> 5, fe = idx & 31;
        const float f = expf(-LN10K * (float)fe / 32.0f);
        const float a = (float)s * f;
        ct[idx] = cosf(a);
        st[idx] = sinf(a);
    }
}

// ---------------------------------------------------------------------------
// Combined MFMA GEMM (m97-style): blocks x<16 compute the QK-projection
// (N=2048, RoPE epilogue -> Q,K); x>=16 the V-projection (N=1024 -> V^T).
// 128x128 tile, BK=64, global_load_lds w=16 with xor-source, swizzled read.
// ---------------------------------------------------------------------------
__global__ __launch_bounds__(256) void gemm_fused_all(
    const ushort* __restrict__ xqkB, const ushort* __restrict__ xvB,
    const ushort* __restrict__ WqkT, const ushort* __restrict__ WvT,
    const float* __restrict__ b_qk, const float* __restrict__ b_v,
    const float* __restrict__ ctab, const float* __restrict__ stab,
    ushort* __restrict__ Qw, ushort* __restrict__ Kw, ushort* __restrict__ Vtw)
{
    __shared__ ushort Asm[128 * 64];   // [row][k] bf16, 128B rows, swizzled
    __shared__ ushort Bsm[128 * 64];

    const bool isQK = blockIdx.x < 16;
    const ushort* A  = isQK ? xqkB : xvB;
    const ushort* Bt = isQK ? WqkT : WvT;
    const float* bias = isQK ? b_qk : b_v;
    const int nbase = (isQK ? blockIdx.x : blockIdx.x - 16) * 128;
    const int mbase = blockIdx.y * 128;

    const int tid = threadIdx.x;
    const int lane = tid & 63, w = tid >> 6;
    const int g = lane >> 4, c = lane & 15;
    const int wm = (w >> 1) * 64, wn = (w & 1) * 64;

    f32x4 acc[4][4];
#pragma unroll
    for (int mf = 0; mf < 4; ++mf)
#pragma unroll
        for (int nf = 0; nf < 4; ++nf)
            acc[mf][nf] = (f32x4){0.f, 0.f, 0.f, 0.f};

    const int sbase = w * 64 + lane;

    for (int k0 = 0; k0 < Kd; k0 += 64) {
#pragma unroll
        for (int j = 0; j < 4; ++j) {
            const int i = j * 256 + sbase;
            const int row = i >> 3, c16 = i & 7;
            const int kc = (c16 ^ (row & 7)) * 8;
            gload16(A + (size_t)(mbase + row) * Kd + k0 + kc,
                    &Asm[(size_t)(j * 256 + w * 64) * 8]);
            gload16(Bt + (size_t)(nbase + row) * Kd + k0 + kc,
                    &Bsm[(size_t)(j * 256 + w * 64) * 8]);
        }
        __syncthreads();

#pragma unroll
        for (int ks = 0; ks < 2; ++ks) {
            bf16x8 af[4], bfr[4];
#pragma unroll
            for (int mf = 0; mf < 4; ++mf) {
                const int row = wm + mf * 16 + c;
                af[mf] = *(const bf16x8*)((const char*)Asm + swz(row, ks * 4 + g));
            }
#pragma unroll
            for (int nf = 0; nf < 4; ++nf) {
                const int row = wn + nf * 16 + c;
                bfr[nf] = *(const bf16x8*)((const char*)Bsm + swz(row, ks * 4 + g));
            }
#pragma unroll
            for (int mf = 0; mf < 4; ++mf)
#pragma unroll
                for (int nf = 0; nf < 4; ++nf)
                    acc[mf][nf] = MFMA16(af[mf], bfr[nf], acc[mf][nf]);
        }
        __syncthreads();
    }

#pragma unroll
    for (int nf = 0; nf < 4; ++nf) {
        const int col = nbase + wn + nf * 16 + c;
        const float bs = bias[col];
        if (isQK) {
            const int dh = col & 63, h = (col >> 6) & 15, isK = col >> 10;
            ushort* dst = isK ? Kw : Qw;
            // Q: fold 1/sqrt(64) * log2(e) so attention exps are exp2
            const float sc = isK ? 1.0f : 0.18033688011112042f;
            const float* cr = ctab + (dh & 31);
            const float* sr = stab + (dh & 31);
#pragma unroll
            for (int mf = 0; mf < 4; ++mf) {
#pragma unroll
                for (int r = 0; r < 4; ++r) {
                    const int row = mbase + wm + mf * 16 + g * 4 + r;
                    const int s = row & 2047, b = row >> 11;
                    const float v = acc[mf][nf][r] + bs;
                    const float p = __shfl_xor(v, 1);
                    const float cs = cr[s * 32], sn = sr[s * 32];
                    const float ov = (c & 1) ? v * cs + p * sn
                                             : v * cs - p * sn;
                    dst[(((size_t)(b * Hn + h)) * Sn + s) * DHn + dh] =
                        f2bf(ov * sc);
                }
            }
        } else {
            const int h = col >> 6, dh = col & 63;
#pragma unroll
            for (int mf = 0; mf < 4; ++mf) {
#pragma unroll
                for (int r = 0; r < 4; ++r) {
                    const int row = mbase + wm + mf * 16 + g * 4 + r;
                    const int s = row & 2047, b = row >> 11;
                    const float v = acc[mf][nf][r] + bs;
                    Vtw[(((size_t)(b * Hn + h)) * DHn + dh) * Sn + s] = f2bf(v);
                }
            }
        }
    }
}

// ---------------------------------------------------------------------------
// MFMA flash attention (round 11 structure — best measured: 80.3 us).
// 32x32 frags, swapped QK^T, permlane P-rebuild, exp2 domain, counted-vmcnt
// triple-buffered pipeline: stage(t+2) after compute(t); per-iter sync is
// s_waitcnt vmcnt(4) + raw s_barrier.
// ---------------------------------------------------------------------------
__global__ __launch_bounds__(256) void attn_mfma(
    const ushort* __restrict__ Qg, const ushort* __restrict__ Kg,
    const ushort* __restrict__ Vtg, float* __restrict__ Aw)
{
    __shared__ char Kt[3][8192];   // [64 kv][64 d] bf16, swizzled
    __shared__ char Vt[3][8192];   // [64 dh][64 kv] bf16, swizzled

    const int tid = threadIdx.x;
    const int lane = tid & 63, w = tid >> 6;
    const int r31 = lane & 31, hi = lane >> 5;
    const int bh = blockIdx.y;
    const int b = bh >> 4, h = bh & 15;
    const int q0 = blockIdx.x * 128 + w * 32;

    // Q B-frags: lane holds Q[q0 + r31][kt*16 + hi*8 + j]
    const ushort* qp = Qg + ((size_t)bh * Sn + q0 + r31) * DHn + hi * 8;
    bf16x8 qf[4];
#pragma unroll
    for (int kt = 0; kt < 4; ++kt)
        qf[kt] = *(const bf16x8*)(qp + kt * 16);

    const ushort* Kb = Kg + (size_t)bh * Sn * DHn;
    const ushort* Vb = Vtg + (size_t)bh * DHn * Sn;

    // stage one 64x64 K tile + one 64x64 V^T tile: 4 gload16 per thread.
    auto stage = [&](int buf, int kb) {
#pragma unroll
        for (int j = 0; j < 2; ++j) {
            const int i = j * 256 + w * 64 + lane;
            const int row = i >> 3, c16 = i & 7;
            const int kc = (c16 ^ (row & 7)) * 8;
            gload16(Kb + (size_t)(kb + row) * DHn + kc,
                    (ushort*)&Kt[buf][(j * 256 + w * 64) * 16]);
            gload16(Vb + (size_t)row * Sn + kb + kc,
                    (ushort*)&Vt[buf][(j * 256 + w * 64) * 16]);
        }
    };

    // prologue: tiles 0 and 1 in flight (8 vmcnt ops/wave outstanding)
    stage(0, 0);
    stage(1, 64);

    f32x16 acc0, acc1;
#pragma unroll
    for (int i = 0; i < 16; ++i) { acc0[i] = 0.f; acc1[i] = 0.f; }
    float m = -1e30f, lp = 0.f;

    const int NT = Sn / 64;   // 32
    for (int t = 0; t < NT; ++t) {
        const int cur = t % 3;

        // ---- wait for buf[cur]'s 4 DMAs (keep the next tile's 4 in flight) --
        if (t < NT - 1) {
            asm volatile("s_waitcnt vmcnt(4)" ::: "memory");
        } else {
            asm volatile("s_waitcnt vmcnt(0)" ::: "memory");
        }
        __builtin_amdgcn_sched_barrier(0);
        __builtin_amdgcn_s_barrier();     // all waves' buf[cur] complete
        __builtin_amdgcn_sched_barrier(0);

        // ---- QK^T swapped: C[kv][q] for two 32-kv tiles ----
        f32x16 C0, C1;
#pragma unroll
        for (int i = 0; i < 16; ++i) { C0[i] = 0.f; C1[i] = 0.f; }
        __builtin_amdgcn_s_setprio(1);
#pragma unroll
        for (int kt = 0; kt < 4; ++kt) {
            const bf16x8 ka = *(const bf16x8*)&Kt[cur][swz(r31, kt * 2 + hi)];
            C0 = MFMA32(ka, qf[kt], C0);
        }
#pragma unroll
        for (int kt = 0; kt < 4; ++kt) {
            const bf16x8 ka = *(const bf16x8*)&Kt[cur][swz(32 + r31, kt * 2 + hi)];
            C1 = MFMA32(ka, qf[kt], C1);
        }
        __builtin_amdgcn_s_setprio(0);

        // ---- row max (q = r31): in-reg tree + partner half ----
        float mx[8];
#pragma unroll
        for (int i = 0; i < 8; ++i)
            mx[i] = fmaxf(fmaxf(C0[i], C0[i + 8]), fmaxf(C1[i], C1[i + 8]));
        mx[0] = fmaxf(mx[0], mx[4]); mx[1] = fmaxf(mx[1], mx[5]);
        mx[2] = fmaxf(mx[2], mx[6]); mx[3] = fmaxf(mx[3], mx[7]);
        float pmax = fmaxf(fmaxf(mx[0], mx[1]), fmaxf(mx[2], mx[3]));
        pmax = fmaxf(pmax, __shfl_xor(pmax, 32));

        // ---- defer-max rescale (rare; threshold 8*log2e) ----
        if (__any(pmax > m + 11.5f)) {
            const float mn = fmaxf(m, pmax);
            const float a = exp2f(m - mn);
            m = mn;
            lp *= a;
#pragma unroll
            for (int reg = 0; reg < 16; ++reg) {
                const int qr = (reg & 3) + 8 * (reg >> 2) + 4 * hi;
                const float ar = __shfl(a, qr);
                acc0[reg] *= ar;
                acc1[reg] *= ar;
            }
        }

        // ---- exp2 + pack + permlane -> PV A-frags ----
        bf16x8 paf[4];
#pragma unroll
        for (int tile = 0; tile < 2; ++tile) {
            const f32x16& C = tile ? C1 : C0;
            float e[16];
#pragma unroll
            for (int i = 0; i < 16; ++i) e[i] = exp2f(C[i] - m);
            float s = 0.f;
#pragma unroll
            for (int i = 0; i < 16; ++i) s += e[i];
            lp += s;
            uint p01 = cvtpk(e[0], e[1]),  p23 = cvtpk(e[2], e[3]);
            uint p45 = cvtpk(e[4], e[5]),  p67 = cvtpk(e[6], e[7]);
            uint p89 = cvtpk(e[8], e[9]),  pab = cvtpk(e[10], e[11]);
            uint pcd = cvtpk(e[12], e[13]), pef = cvtpk(e[14], e[15]);
            plswap(p01, p45); plswap(p23, p67);   // kt0: kv 0-15
            plswap(p89, pcd); plswap(pab, pef);   // kt1: kv 16-31
            uint4 f0 = {p01, p23, p45, p67};
            uint4 f1 = {p89, pab, pcd, pef};
            paf[tile * 2 + 0] = *(const bf16x8*)&f0;
            paf[tile * 2 + 1] = *(const bf16x8*)&f1;
        }

        // ---- PV: O[q][dh], 2 dh-tiles x 4 k-frags ----
        __builtin_amdgcn_s_setprio(1);
#pragma unroll
        for (int kf = 0; kf < 4; ++kf) {
            const bf16x8 v0 = *(const bf16x8*)&Vt[cur][swz(r31, kf * 2 + hi)];
            acc0 = MFMA32(paf[kf], v0, acc0);
        }
#pragma unroll
        for (int kf = 0; kf < 4; ++kf) {
            const bf16x8 v1 = *(const bf16x8*)&Vt[cur][swz(32 + r31, kf * 2 + hi)];
            acc1 = MFMA32(paf[kf], v1, acc1);
        }
        __builtin_amdgcn_s_setprio(0);

        // ---- issue stage for tile t+2 (buffer safe: its last readers were
        //      iter t-1, and barrier-t proved they're done) ----
        __builtin_amdgcn_sched_barrier(0);
        if (t + 2 < NT) stage((t + 2) % 3, (t + 2) * 64);
    }

    // ---- epilogue: reduce lp across halves, redistribute, store ----
    const float lv = lp + __shfl_xor(lp, 32);
    const float inv = 1.0f / lv;      // for q = r31
#pragma unroll
    for (int reg = 0; reg < 16; ++reg) {
        const int qr = (reg & 3) + 8 * (reg >> 2) + 4 * hi;
        const float ir = __shfl(inv, qr);
        const int qs = q0 + qr;
        float* dst = &Aw[((size_t)b * Sn + qs) * Dn + h * DHn + r31];
        dst[0]  = acc0[reg] * ir;
        dst[32] = acc1[reg] * ir;
    }
}

// ---------------------------------------------------------------------------
// LayerNorm over D=1024 per (b,s) row; f32 output.
// ---------------------------------------------------------------------------
__global__ __launch_bounds__(256) void ln_kernel(
    const float* __restrict__ Aw, const float* __restrict__ gamma,
    const float* __restrict__ beta, float* __restrict__ out)
{
    const int row = blockIdx.x;
    const int tid = threadIdx.x;
    const int d0 = tid * 4;
    const float4 x = *(const float4*)&Aw[(size_t)row * Dn + d0];
    float sum = x.x + x.y + x.z + x.w;
    float sq = x.x * x.x + x.y * x.y + x.z * x.z + x.w * x.w;
    for (int off = 32; off; off >>= 1) {
        sum += __shfl_xor(sum, off);
        sq += __shfl_xor(sq, off);
    }
    __shared__ float red[8];
    const int lane = tid & 63, wave = tid >> 6;
    if (lane == 0) { red[wave] = sum; red[wave + 4] = sq; }
    __syncthreads();
    if (tid == 0) {
        red[0] = red[0] + red[1] + red[2] + red[3];
        red[4] = red[4] + red[5] + red[6] + red[7];
    }
    __syncthreads();
    sum = red[0]; sq = red[4];
    const float mu = sum * (1.0f / Dn);
    const float var = sq * (1.0f / Dn) - mu * mu;
    const float rs = rsqrtf(var + 1e-5f);

    const float4 gv = *(const float4*)&gamma[d0];
    const float4 bv = *(const float4*)&beta[d0];
    float4 ov;
    ov.x = (x.x - mu) * rs * gv.x + bv.x;
    ov.y = (x.y - mu) * rs * gv.y + bv.y;
    ov.z = (x.z - mu) * rs * gv.z + bv.z;
    ov.w = (x.w - mu) * rs * gv.w + bv.w;
    *(float4*)&out[(size_t)row * Dn + d0] = ov;
}

extern "C" void kernel_launch(void* const* d_in, const int* in_sizes, int n_in,
                              void* d_out, int out_size, void* d_ws, size_t ws_size,
                              hipStream_t stream)
{
    const float* x_qk = (const float*)d_in[0];
    const float* x_v  = (const float*)d_in[1];
    const float* W_qk = (const float*)d_in[2];
    const float* b_qk = (const float*)d_in[3];
    const float* W_v  = (const float*)d_in[4];
    const float* b_v  = (const float*)d_in[5];
    const float* g    = (const float*)d_in[6];
    const float* be   = (const float*)d_in[7];

    char* ws = (char*)d_ws;
    ushort* Qw    = (ushort*)(ws);                  //  8 MB bf16 (b,h,s,dh)
    ushort* Kw    = (ushort*)(ws + (8u  << 20));    //  8 MB bf16 (b,h,s,dh)
    ushort* Vtw   = (ushort*)(ws + (16u << 20));    //  8 MB bf16 (b,h,dh,s)
    float*  Aw    = (float*) (ws + (24u << 20));    // 16 MB f32  (b,s,D)
    ushort* xqkB  = (ushort*)(ws + (40u << 20));    //  8 MB bf16 [M][K]
    ushort* xvB   = (ushort*)(ws + (48u << 20));    //  8 MB bf16 [M][K]
    ushort* WqkT  = (ushort*)(ws + (56u << 20));    //  4 MB bf16 [2048][1024]
    ushort* WvT   = (ushort*)(ws + (60u << 20));    //  2 MB bf16 [1024][1024]
    float*  ctab  = (float*) (ws + (62u << 20));    // 256 KB
    float*  stab  = (float*) (ws + (62u << 20) + (256u << 10));

    // 1) fused prep: cvt x2 + transpose x2 + RoPE table
    prep<<<7424, 256, 0, stream>>>(x_qk, x_v, W_qk, W_v,
                                   xqkB, xvB, WqkT, WvT, ctab, stab);
    // 2) both projections in one dispatch (x<16: QK+RoPE, x>=16: V^T)
    gemm_fused_all<<<dim3(24, 32), 256, 0, stream>>>(
        xqkB, xvB, WqkT, WvT, b_qk, b_v, ctab, stab, Qw, Kw, Vtw);
    // 3) flash attention (round-11 structure)
    attn_mfma<<<dim3(16, 32), 256, 0, stream>>>(Qw, Kw, Vtw, Aw);
    // 4) LayerNorm
    ln_kernel<<<Bn * Sn, 256, 0, stream>>>(Aw, g, be, (float*)d_out);
}